// Round 18
// baseline (194.584 us; speedup 1.0000x reference)
//
#include <hip/hip_runtime.h>
#include <math.h>

// Problem constants (match reference file)
#define NN   8192   // nodes
#define DF   64     // feature dim
#define KK   16     // k samples
#define MAXNBR 33   // self + up to 32 neighbors (row has <= 32 ones)
#define NT   256    // threads per block (4 waves)
#define NPB  4      // nodes per block; grid = 2048 = exactly 8 blocks/CU resident
#define NBINS 2048  // histogram bins = top 11 bits of flipped-float key
#define MAXC 544
#define NR   9      // fixed phase-D trip count: c0 = 4g + 64r < 528 for all g
// transposed layout: thread t sums bins 8t..8t+7 conflict-free
#define HIDX(b) ((((b) & 7) << 8) | ((b) >> 3))

typedef unsigned uvec4 __attribute__((ext_vector_type(4)));  // NT-load-compatible

// Block barrier that does NOT drain vmcnt: all intra-block communication is
// LDS, so lgkmcnt(0)+s_barrier is sufficient; in-flight global (stream) loads
// survive across it. (__syncthreads would emit vmcnt(0) and kill the overlap.)
__device__ __forceinline__ void lds_barrier() {
    asm volatile("s_waitcnt lgkmcnt(0)\n\ts_barrier" ::: "memory");
}

__device__ __forceinline__ unsigned long long kmax(unsigned long long a, unsigned long long b) {
    return a > b ? a : b;
}
__device__ __forceinline__ unsigned long long kmin(unsigned long long a, unsigned long long b) {
    return a > b ? b : a;
}

// 16-lane (DPP-row) tree sum via row_ror adds — VALU pipe only, no DS traffic.
__device__ __forceinline__ float row_reduce16(float acc) {
    acc += __uint_as_float(__builtin_amdgcn_update_dpp(
        0, (int)__float_as_uint(acc), 0x128, 0xF, 0xF, true));   // row_ror:8
    acc += __uint_as_float(__builtin_amdgcn_update_dpp(
        0, (int)__float_as_uint(acc), 0x124, 0xF, 0xF, true));   // row_ror:4
    acc += __uint_as_float(__builtin_amdgcn_update_dpp(
        0, (int)__float_as_uint(acc), 0x122, 0xF, 0xF, true));   // row_ror:2
    acc += __uint_as_float(__builtin_amdgcn_update_dpp(
        0, (int)__float_as_uint(acc), 0x121, 0xF, 0xF, true));   // row_ror:1
    return acc;
}

// full 64-lane bitonic sort, descending (validated R7/R8/R10/R11)
__device__ __forceinline__ void sort64_desc(unsigned long long& kv, int lane) {
    #pragma unroll
    for (int k = 2; k <= 64; k <<= 1) {
        #pragma unroll
        for (int j = k >> 1; j > 0; j >>= 1) {
            unsigned long long o = __shfl_xor(kv, j);
            bool tmax = (((lane & j) == 0) != ((lane & k) != 0));
            kv = tmax ? kmax(kv, o) : kmin(kv, o);
        }
    }
}

__global__ __launch_bounds__(NT, 8)
void fused_kernel(const float* __restrict__ x,
                  const uvec4* __restrict__ adj4,
                  const int*   __restrict__ cs,
                  int*         __restrict__ out)
{
    const int t    = threadIdx.x;
    const int w    = t >> 6;
    const int lane = t & 63;
    const int n0   = blockIdx.x * NPB;

    __shared__ unsigned mask[NN / 32];                  // 1 KB dedup bitmap
    __shared__ int nbrs[MAXNBR];
    __shared__ int cnts[4];                             // 0=nnbr 1=ncand 2=nsurv 3=B
    __shared__ alignas(16) int cand[MAXC];
    __shared__ unsigned long long histsurv[NBINS / 2];  // 8 KB: hist u32[2048] / surv u64
    __shared__ unsigned sum256[NT];
    unsigned* const hist = reinterpret_cast<unsigned*>(histsurv);
    unsigned long long* const surv = histsurv;

    uvec4 v[8];                                         // one 32 KB row in registers

    // ---- prologue: issue row n0, clear state under the load latency ----
    {
        const uvec4* __restrict__ r4 = adj4 + (size_t)n0 * (NN / 4);
        #pragma unroll
        for (int u = 0; u < 8; ++u) v[u] = __builtin_nontemporal_load(&r4[t + NT * u]);
    }
    if (t < NN / 32) mask[t] = 0u;
    #pragma unroll
    for (int r = 0; r < 4; ++r) histsurv[t + NT * r] = 0ULL;
    cand[t] = 0; cand[t + NT] = 0;
    if (t < MAXC - 2 * NT) cand[t + 2 * NT] = 0;
    if (t == 0) { nbrs[0] = n0; cnts[0] = 1; cnts[1] = 0; cnts[2] = 0; }
    lds_barrier();
    asm volatile("s_waitcnt vmcnt(0)" ::: "memory");    // row n0 arrived
    #pragma unroll
    for (int u = 0; u < 8; ++u) {
        if ((v[u].x | v[u].y | v[u].z | v[u].w) != 0u) {
            const int base = 4 * (t + NT * u);
            const unsigned e[4] = {v[u].x, v[u].y, v[u].z, v[u].w};
            #pragma unroll
            for (int c2 = 0; c2 < 4; ++c2)
                if (e[c2] != 0u) {
                    int s = atomicAdd(&cnts[0], 1);
                    if (s < MAXNBR) nbrs[s] = base + c2;
                }
        }
    }
    lds_barrier();

    for (int k = 0; k < NPB; ++k) {
        const int node = n0 + k;
        const bool more = (k + 1 < NPB);

        const int M = min(cnts[0], MAXNBR);
        const int total = M * KK;                       // <= 528

        // ---- phase C: gather cs, dedup via bitmap, append uniques ----
        #pragma unroll
        for (int r = 0; r < 2; ++r) {
            int q = t + NT * r;
            if (q < total) {
                int vv = cs[(size_t)nbrs[q >> 4] * KK + (q & 15)];
                unsigned bit = 1u << (vv & 31);
                unsigned old = atomicOr(&mask[vv >> 5], bit);
                if (!(old & bit)) { int s = atomicAdd(&cnts[1], 1); cand[s] = vv; }
            }
        }
        const int q2 = 2 * NT + (t - 64);               // 512..527 for t=64..79
        if (t >= 64 && t < 80 && q2 < total) {
            int vv = cs[(size_t)nbrs[q2 >> 4] * KK + (q2 & 15)];
            unsigned bit = 1u << (vv & 31);
            unsigned old = atomicOr(&mask[vv >> 5], bit);
            if (!(old & bit)) { int s = atomicAdd(&cnts[1], 1); cand[s] = vv; }
        }
        lds_barrier();

        const int ncv = cnts[1];

        // ---- phase D: sims (R16: int4 cand read, DPP reduce, register keys) ----
        const int g  = t >> 4;
        const int gl = t & 15;
        const float4 xi4 = reinterpret_cast<const float4*>(x + (size_t)node * DF)[gl];
        unsigned long long rkeys[NR];
        #pragma unroll
        for (int r = 0; r < NR; ++r) {
            unsigned long long key = 0ULL;
            const int c0 = 4 * g + 64 * r;
            if (c0 < ncv) {
                const int4 c4 = *reinterpret_cast<const int4*>(&cand[c0]);
                const float4 xv0 = reinterpret_cast<const float4*>(x + (size_t)c4.x * DF)[gl];
                const float4 xv1 = reinterpret_cast<const float4*>(x + (size_t)c4.y * DF)[gl];
                const float4 xv2 = reinterpret_cast<const float4*>(x + (size_t)c4.z * DF)[gl];
                const float4 xv3 = reinterpret_cast<const float4*>(x + (size_t)c4.w * DF)[gl];
                float a0 = 0.f, a1 = 0.f, a2 = 0.f, a3 = 0.f;
                a0 = fmaf(xi4.x, xv0.x, a0); a0 = fmaf(xi4.y, xv0.y, a0);
                a0 = fmaf(xi4.z, xv0.z, a0); a0 = fmaf(xi4.w, xv0.w, a0);
                a1 = fmaf(xi4.x, xv1.x, a1); a1 = fmaf(xi4.y, xv1.y, a1);
                a1 = fmaf(xi4.z, xv1.z, a1); a1 = fmaf(xi4.w, xv1.w, a1);
                a2 = fmaf(xi4.x, xv2.x, a2); a2 = fmaf(xi4.y, xv2.y, a2);
                a2 = fmaf(xi4.z, xv2.z, a2); a2 = fmaf(xi4.w, xv2.w, a2);
                a3 = fmaf(xi4.x, xv3.x, a3); a3 = fmaf(xi4.y, xv3.y, a3);
                a3 = fmaf(xi4.z, xv3.z, a3); a3 = fmaf(xi4.w, xv3.w, a3);
                a0 = row_reduce16(a0);
                a1 = row_reduce16(a1);
                a2 = row_reduce16(a2);
                a3 = row_reduce16(a3);
                if (gl < 4 && c0 + gl < ncv) {
                    float av = (gl == 0) ? a0 : (gl == 1) ? a1 : (gl == 2) ? a2 : a3;
                    int  vb = (gl == 0) ? c4.x : (gl == 1) ? c4.y : (gl == 2) ? c4.z : c4.w;
                    unsigned fb = __float_as_uint(av);
                    fb = (fb & 0x80000000u) ? ~fb : (fb | 0x80000000u);
                    key = ((unsigned long long)fb << 13) |
                          (unsigned long long)(unsigned)(8191 - vb);
                    atomicAdd(&hist[HIDX((unsigned)(key >> 34))], 1u);
                }
            }
            rkeys[r] = key;
        }
        lds_barrier();                                  // hist complete

        // ---- issue next row NOW: flies during F/G/H/clears (LDS+VALU only);
        //      lds_barrier() does not drain vmcnt, so these stay in flight ----
        if (more) {
            const uvec4* __restrict__ r4 = adj4 + (size_t)(node + 1) * (NN / 4);
            #pragma unroll
            for (int u = 0; u < 8; ++u) v[u] = __builtin_nontemporal_load(&r4[t + NT * u]);
        }

        if (ncv >= KK) {
            // ---- phase F: find bin B of the 16th-largest key ----
            unsigned s8 = 0;
            #pragma unroll
            for (int j = 0; j < 8; ++j) s8 += hist[(j << 8) | t];
            sum256[t] = s8;
            lds_barrier();
            if (w == 0) {
                const int c = 63 - lane;
                unsigned c32 = 0;
                #pragma unroll
                for (int j = 0; j < 4; ++j) c32 += sum256[4 * c + j];
                unsigned p = c32;
                #pragma unroll
                for (int off = 1; off < 64; off <<= 1) {
                    unsigned o = __shfl_up(p, off);
                    if (lane >= off) p += o;
                }
                unsigned long long bal = __ballot(p >= (unsigned)KK);
                int l1 = (int)__ffsll((unsigned long long)bal) - 1;
                unsigned above1 = __shfl(p - c32, l1);
                int C = 63 - l1;
                int b = 32 * C + 31 - lane;
                unsigned hb = (lane < 32) ? hist[HIDX(b)] : 0u;
                unsigned p2 = hb;
                #pragma unroll
                for (int off = 1; off < 64; off <<= 1) {
                    unsigned o = __shfl_up(p2, off);
                    if (lane >= off) p2 += o;
                }
                unsigned long long bal2 = __ballot(above1 + p2 >= (unsigned)KK);
                int l2 = (int)__ffsll((unsigned long long)bal2) - 1;
                if (lane == 0) cnts[3] = 32 * C + 31 - l2;
            }
            lds_barrier();                              // hist now dead
            const unsigned Bv = (unsigned)cnts[3];

            // ---- phase G: survivors from registers; surv aliases dead hist ----
            #pragma unroll
            for (int r = 0; r < NR; ++r) {
                unsigned long long kq = rkeys[r];
                if (kq != 0ULL && (unsigned)(kq >> 34) >= Bv) {
                    int s = atomicAdd(&cnts[2], 1);
                    surv[s] = kq;
                }
            }
            lds_barrier();

            // ---- phase H: wave 0 sorts survivors exactly ----
            if (w == 0) {
                const int S = cnts[2];
                unsigned long long kk = (lane < S) ? surv[lane] : 0ULL;
                sort64_desc(kk, lane);
                int processed = 64;
                while (processed < S) {
                    if (lane >= 16) {
                        int idx = processed + (lane - 16);
                        kk = (idx < S) ? surv[idx] : 0ULL;
                    }
                    sort64_desc(kk, lane);
                    processed += 48;
                }
                if (lane < KK)
                    out[(size_t)node * KK + lane] = 8191 - (int)(kk & 0x1FFFULL);
            }
        } else {
            // rare: fewer than K uniques -> sorted uniques + pad with own samples
            if (t == 0) {
                int sorted_u[KK];
                int cnt2 = 0;
                for (int mw = 0; mw < NN / 32 && cnt2 < KK; ++mw) {
                    unsigned b = mask[mw];
                    while (b && cnt2 < KK) {
                        int bit = __ffs(b) - 1;
                        b &= b - 1;
                        sorted_u[cnt2++] = mw * 32 + bit;
                    }
                }
                for (int j = 0; j < KK; ++j) {
                    int uu;
                    if (j < ncv) {
                        uu = sorted_u[j];
                    } else {
                        int idx = j - ncv;
                        if (idx > KK - 1) idx = KK - 1;
                        uu = cs[(size_t)node * KK + idx];
                    }
                    out[(size_t)node * KK + j] = uu;
                }
            }
        }
        lds_barrier();                                  // everyone done with mask/surv

        if (more) {
            // ---- clears for node k+1 (stream still in flight) ----
            if (t < NN / 32) mask[t] = 0u;
            #pragma unroll
            for (int r = 0; r < 4; ++r) histsurv[t + NT * r] = 0ULL;
            cand[t] = 0; cand[t + NT] = 0;
            if (t < MAXC - 2 * NT) cand[t + 2 * NT] = 0;
            if (t == 0) { nbrs[0] = node + 1; cnts[0] = 1; cnts[1] = 0; cnts[2] = 0; }
            lds_barrier();
            // ---- extract: the only vmcnt drain in the loop ----
            asm volatile("s_waitcnt vmcnt(0)" ::: "memory");
            #pragma unroll
            for (int u = 0; u < 8; ++u) {
                if ((v[u].x | v[u].y | v[u].z | v[u].w) != 0u) {
                    const int base = 4 * (t + NT * u);
                    const unsigned e[4] = {v[u].x, v[u].y, v[u].z, v[u].w};
                    #pragma unroll
                    for (int c2 = 0; c2 < 4; ++c2)
                        if (e[c2] != 0u) {
                            int s = atomicAdd(&cnts[0], 1);
                            if (s < MAXNBR) nbrs[s] = base + c2;
                        }
                }
            }
            lds_barrier();
        }
    }
}

extern "C" void kernel_launch(void* const* d_in, const int* in_sizes, int n_in,
                              void* d_out, int out_size, void* d_ws, size_t ws_size,
                              hipStream_t stream)
{
    const float* x   = (const float*)d_in[0];
    const float* adj = (const float*)d_in[1];
    const int*   cs  = (const int*)d_in[2];
    int* out = (int*)d_out;

    fused_kernel<<<NN / NPB, NT, 0, stream>>>(
        x, reinterpret_cast<const uvec4*>(adj), cs, out);
}

// Round 19
// 86.598 us; speedup vs baseline: 2.2470x; 2.2470x over previous
//
#include <hip/hip_runtime.h>
#include <math.h>

// Problem constants (match reference file)
#define NN   8192   // nodes
#define DF   64     // feature dim
#define KK   16     // k samples
#define MAXNBR 33   // self + up to 32 neighbors (row has <= 32 ones)
#define NT   256    // threads per block (4 waves)
#define NBINS 2048  // histogram bins = top 11 bits of flipped-float key
#define MAXC 544
#define NR   9      // fixed phase-D trip count: c0 = 4g + 64r < 528 for all g
// transposed layout: thread t sums bins 8t..8t+7 conflict-free
#define HIDX(b) ((((b) & 7) << 8) | ((b) >> 3))

typedef unsigned uvec4 __attribute__((ext_vector_type(4)));  // NT-load-compatible

__device__ __forceinline__ unsigned long long kmax(unsigned long long a, unsigned long long b) {
    return a > b ? a : b;
}
__device__ __forceinline__ unsigned long long kmin(unsigned long long a, unsigned long long b) {
    return a > b ? b : a;
}

// 16-lane (DPP-row) tree sum via row_ror adds — VALU pipe only, no DS traffic.
// Pairing/order is bit-identical to the xor{8,4,2,1} shuffle tree (R11-passing).
// After this, ALL 16 lanes of the row hold the full sum.
__device__ __forceinline__ float row_reduce16(float acc) {
    acc += __uint_as_float(__builtin_amdgcn_update_dpp(
        0, (int)__float_as_uint(acc), 0x128, 0xF, 0xF, true));   // row_ror:8
    acc += __uint_as_float(__builtin_amdgcn_update_dpp(
        0, (int)__float_as_uint(acc), 0x124, 0xF, 0xF, true));   // row_ror:4
    acc += __uint_as_float(__builtin_amdgcn_update_dpp(
        0, (int)__float_as_uint(acc), 0x122, 0xF, 0xF, true));   // row_ror:2
    acc += __uint_as_float(__builtin_amdgcn_update_dpp(
        0, (int)__float_as_uint(acc), 0x121, 0xF, 0xF, true));   // row_ror:1
    return acc;
}

// full 64-lane bitonic sort, descending (validated R7/R8/R10/R11)
__device__ __forceinline__ void sort64_desc(unsigned long long& kv, int lane) {
    #pragma unroll
    for (int k = 2; k <= 64; k <<= 1) {
        #pragma unroll
        for (int j = k >> 1; j > 0; j >>= 1) {
            unsigned long long o = __shfl_xor(kv, j);
            bool tmax = (((lane & j) == 0) != ((lane & k) != 0));
            kv = tmax ? kmax(kv, o) : kmin(kv, o);
        }
    }
}

// ---- one block (4 waves) per node ----
__global__ __launch_bounds__(NT, 8)
void fused_kernel(const float* __restrict__ x,
                  const uvec4* __restrict__ adj4,
                  const int*   __restrict__ cs,
                  int*         __restrict__ out)
{
    const int i    = blockIdx.x;           // node id
    const int t    = threadIdx.x;
    const int w    = t >> 6;
    const int lane = t & 63;

    __shared__ unsigned mask[NN / 32];                  // 1 KB dedup bitmap
    __shared__ int nbrs[MAXNBR];
    __shared__ int nnbr;
    __shared__ alignas(16) int cand[MAXC];              // unique candidate values
    __shared__ int ncand;
    __shared__ unsigned long long histsurv[NBINS / 2];  // 8 KB: hist (u32x2048) then surv (u64x544)
    __shared__ unsigned sum256[NT];                     // stage-1 partial sums
    __shared__ int nsurv;
    __shared__ int B_sh;
    unsigned* const hist = reinterpret_cast<unsigned*>(histsurv);
    unsigned long long* const surv = histsurv;

    // ---- phase A: init (cand zero-filled: safe prefetch addresses past ncv) ----
    if (t < NN / 32) mask[t] = 0u;                      // 256 words
    #pragma unroll
    for (int r = 0; r < 4; ++r) histsurv[t + NT * r] = 0ULL;  // clears 2048 u32 bins
    cand[t] = 0; cand[t + NT] = 0;
    if (t < MAXC - 2 * NT) cand[t + 2 * NT] = 0;
    if (t == 0) { nbrs[0] = i; nnbr = 1; ncand = 0; nsurv = 0; }
    __syncthreads();                                    // barrier 1

    // ---- phase B: scan row i — 2048 uint4s, 8/thread, NON-TEMPORAL ----
    const uvec4* __restrict__ row4 = adj4 + (size_t)i * (NN / 4);
    uvec4 v[8];
    #pragma unroll
    for (int u = 0; u < 8; ++u) v[u] = __builtin_nontemporal_load(&row4[t + NT * u]);
    #pragma unroll
    for (int u = 0; u < 8; ++u) {
        if ((v[u].x | v[u].y | v[u].z | v[u].w) != 0u) {    // 1.0f == 0x3F800000
            const int base = 4 * (t + NT * u);
            const unsigned e[4] = {v[u].x, v[u].y, v[u].z, v[u].w};
            #pragma unroll
            for (int c2 = 0; c2 < 4; ++c2) {
                if (e[c2] != 0u) {
                    int s = atomicAdd(&nnbr, 1);
                    if (s < MAXNBR) nbrs[s] = base + c2;
                }
            }
        }
    }
    __syncthreads();                                    // barrier 2

    const int M = min(nnbr, MAXNBR);

    // ---- phase C: COALESCED cs gather — thread t reads one int4 of row
    //      nbrs[t>>2] (4 cands/lane, ~132 coalesced txns vs 528 scattered) ----
    if (t < 4 * M) {
        const int j = t >> 2, q = t & 3;
        const int4 cq = *reinterpret_cast<const int4*>(
            &cs[(size_t)nbrs[j] * KK + 4 * q]);         // 16B aligned (64B rows)
        const int vals[4] = {cq.x, cq.y, cq.z, cq.w};
        #pragma unroll
        for (int e = 0; e < 4; ++e) {
            int vv = vals[e];
            unsigned bit = 1u << (vv & 31);
            unsigned old = atomicOr(&mask[vv >> 5], bit);
            if (!(old & bit)) { int s = atomicAdd(&ncand, 1); cand[s] = vv; }
        }
    }
    __syncthreads();                                    // barrier 3

    const int ncv = ncand;                              // unique count

    // ---- phase D: sims — 16-lane groups, 4 candidates per int4 LDS read,
    //      DPP row-reduce; keys kept in REGISTERS (no skeys LDS) ----
    const int g  = t >> 4;                              // 16 groups
    const int gl = t & 15;                              // lane in group
    const float4 xi4 = reinterpret_cast<const float4*>(x + (size_t)i * DF)[gl];
    unsigned long long rkeys[NR];                       // statically indexed
    #pragma unroll
    for (int r = 0; r < NR; ++r) {
        unsigned long long key = 0ULL;
        const int c0 = 4 * g + 64 * r;
        if (c0 < ncv) {
            const int4 c4 = *reinterpret_cast<const int4*>(&cand[c0]);  // ds_read_b128
            const float4 xv0 = reinterpret_cast<const float4*>(x + (size_t)c4.x * DF)[gl];
            const float4 xv1 = reinterpret_cast<const float4*>(x + (size_t)c4.y * DF)[gl];
            const float4 xv2 = reinterpret_cast<const float4*>(x + (size_t)c4.z * DF)[gl];
            const float4 xv3 = reinterpret_cast<const float4*>(x + (size_t)c4.w * DF)[gl];
            float a0 = 0.f, a1 = 0.f, a2 = 0.f, a3 = 0.f;
            a0 = fmaf(xi4.x, xv0.x, a0); a0 = fmaf(xi4.y, xv0.y, a0);
            a0 = fmaf(xi4.z, xv0.z, a0); a0 = fmaf(xi4.w, xv0.w, a0);
            a1 = fmaf(xi4.x, xv1.x, a1); a1 = fmaf(xi4.y, xv1.y, a1);
            a1 = fmaf(xi4.z, xv1.z, a1); a1 = fmaf(xi4.w, xv1.w, a1);
            a2 = fmaf(xi4.x, xv2.x, a2); a2 = fmaf(xi4.y, xv2.y, a2);
            a2 = fmaf(xi4.z, xv2.z, a2); a2 = fmaf(xi4.w, xv2.w, a2);
            a3 = fmaf(xi4.x, xv3.x, a3); a3 = fmaf(xi4.y, xv3.y, a3);
            a3 = fmaf(xi4.z, xv3.z, a3); a3 = fmaf(xi4.w, xv3.w, a3);
            a0 = row_reduce16(a0);                      // all 16 lanes get the sum
            a1 = row_reduce16(a1);
            a2 = row_reduce16(a2);
            a3 = row_reduce16(a3);
            // lane gl (< 4) owns candidate c0+gl: one key per lane, in registers
            if (gl < 4 && c0 + gl < ncv) {
                float av = (gl == 0) ? a0 : (gl == 1) ? a1 : (gl == 2) ? a2 : a3;
                int  vb = (gl == 0) ? c4.x : (gl == 1) ? c4.y : (gl == 2) ? c4.z : c4.w;
                unsigned fb = __float_as_uint(av);
                fb = (fb & 0x80000000u) ? ~fb : (fb | 0x80000000u);  // order-preserving
                key = ((unsigned long long)fb << 13) |
                      (unsigned long long)(unsigned)(8191 - vb);
                atomicAdd(&hist[HIDX((unsigned)(key >> 34))], 1u);   // 16 lanes, 1 instr
            }
        }
        rkeys[r] = key;                                 // 0 = invalid (unreachable code)
    }
    __syncthreads();                                    // barrier 4

    if (ncv >= KK) {
        // ---- phase F: find bin B containing the 16th-largest key ----
        unsigned s8 = 0;
        #pragma unroll
        for (int j = 0; j < 8; ++j) s8 += hist[(j << 8) | t];   // bins 8t..8t+7
        sum256[t] = s8;
        __syncthreads();                                // barrier 5
        if (w == 0) {
            // stage 2: 64 chunks of 32 bins, scanned from top
            const int c = 63 - lane;
            unsigned c32 = 0;
            #pragma unroll
            for (int j = 0; j < 4; ++j) c32 += sum256[4 * c + j];
            unsigned p = c32;
            #pragma unroll
            for (int off = 1; off < 64; off <<= 1) {
                unsigned o = __shfl_up(p, off);
                if (lane >= off) p += o;
            }
            unsigned long long bal = __ballot(p >= (unsigned)KK);
            int l1 = (int)__ffsll((unsigned long long)bal) - 1;
            unsigned above1 = __shfl(p - c32, l1);
            int C = 63 - l1;
            // stage 3: 32 bins of chunk C, descending
            int b = 32 * C + 31 - lane;
            unsigned hb = (lane < 32) ? hist[HIDX(b)] : 0u;
            unsigned p2 = hb;
            #pragma unroll
            for (int off = 1; off < 64; off <<= 1) {
                unsigned o = __shfl_up(p2, off);
                if (lane >= off) p2 += o;
            }
            unsigned long long bal2 = __ballot(above1 + p2 >= (unsigned)KK);
            int l2 = (int)__ffsll((unsigned long long)bal2) - 1;
            if (lane == 0) B_sh = 32 * C + 31 - l2;
        }
        __syncthreads();                                // barrier 6 (hist now dead)
        const unsigned Bv = (unsigned)B_sh;

        // ---- phase G: append survivors from REGISTERS; surv aliases dead hist ----
        #pragma unroll
        for (int r = 0; r < NR; ++r) {
            unsigned long long k = rkeys[r];
            if (k != 0ULL && (unsigned)(k >> 34) >= Bv) {
                int s = atomicAdd(&nsurv, 1);
                surv[s] = k;
            }
        }
        __syncthreads();                                // barrier 7

        // ---- phase H: wave 0 sorts survivors exactly (u64 keys) ----
        if (w == 0) {
            const int S = nsurv;                        // >= 16 by construction
            unsigned long long kk = (lane < S) ? surv[lane] : 0ULL;
            sort64_desc(kk, lane);
            int processed = 64;
            while (processed < S) {                     // rare fallback: chunked resort
                if (lane >= 16) {
                    int idx = processed + (lane - 16);
                    kk = (idx < S) ? surv[idx] : 0ULL;
                }
                sort64_desc(kk, lane);
                processed += 48;
            }
            if (lane < KK)
                out[(size_t)i * KK + lane] = 8191 - (int)(kk & 0x1FFFULL);
        }
    } else {
        // rare: fewer than K uniques -> sorted uniques + pad with own samples
        if (t == 0) {
            int sorted_u[KK];
            int cnt2 = 0;
            for (int mw = 0; mw < NN / 32 && cnt2 < KK; ++mw) {
                unsigned b = mask[mw];
                while (b && cnt2 < KK) {
                    int bit = __ffs(b) - 1;
                    b &= b - 1;
                    sorted_u[cnt2++] = mw * 32 + bit;
                }
            }
            for (int j = 0; j < KK; ++j) {
                int uu;
                if (j < ncv) {
                    uu = sorted_u[j];
                } else {
                    int idx = j - ncv;
                    if (idx > KK - 1) idx = KK - 1;
                    uu = cs[(size_t)i * KK + idx];
                }
                out[(size_t)i * KK + j] = uu;
            }
        }
    }
}

extern "C" void kernel_launch(void* const* d_in, const int* in_sizes, int n_in,
                              void* d_out, int out_size, void* d_ws, size_t ws_size,
                              hipStream_t stream)
{
    const float* x   = (const float*)d_in[0];
    const float* adj = (const float*)d_in[1];
    const int*   cs  = (const int*)d_in[2];
    int* out = (int*)d_out;

    fused_kernel<<<NN, NT, 0, stream>>>(
        x, reinterpret_cast<const uvec4*>(adj), cs, out);
}

// Round 20
// 82.722 us; speedup vs baseline: 2.3523x; 1.0469x over previous
//
#include <hip/hip_runtime.h>
#include <math.h>

// Problem constants (match reference file)
#define NN   8192   // nodes
#define DF   64     // feature dim
#define KK   16     // k samples
#define MAXNBR 33   // self + up to 32 neighbors (row has <= 32 ones)
#define NT   256    // threads per block (4 waves)
#define NBINS 2048  // histogram bins = top 11 bits of flipped-float key
#define MAXC 544
#define NR   9      // fixed phase-D trip count: c0 = 4g + 64r < 528 for all g
// transposed layout: thread t sums bins 8t..8t+7 conflict-free
#define HIDX(b) ((((b) & 7) << 8) | ((b) >> 3))

typedef unsigned uvec4 __attribute__((ext_vector_type(4)));  // NT-load-compatible

__device__ __forceinline__ unsigned long long kmax(unsigned long long a, unsigned long long b) {
    return a > b ? a : b;
}
__device__ __forceinline__ unsigned long long kmin(unsigned long long a, unsigned long long b) {
    return a > b ? b : a;
}

// 16-lane (DPP-row) tree sum via row_ror adds — VALU pipe only, no DS traffic.
// Pairing/order is bit-identical to the xor{8,4,2,1} shuffle tree (R11-passing).
// After this, ALL 16 lanes of the row hold the full sum.
__device__ __forceinline__ float row_reduce16(float acc) {
    acc += __uint_as_float(__builtin_amdgcn_update_dpp(
        0, (int)__float_as_uint(acc), 0x128, 0xF, 0xF, true));   // row_ror:8
    acc += __uint_as_float(__builtin_amdgcn_update_dpp(
        0, (int)__float_as_uint(acc), 0x124, 0xF, 0xF, true));   // row_ror:4
    acc += __uint_as_float(__builtin_amdgcn_update_dpp(
        0, (int)__float_as_uint(acc), 0x122, 0xF, 0xF, true));   // row_ror:2
    acc += __uint_as_float(__builtin_amdgcn_update_dpp(
        0, (int)__float_as_uint(acc), 0x121, 0xF, 0xF, true));   // row_ror:1
    return acc;
}

// full 64-lane bitonic sort, descending (validated R7/R8/R10/R11)
__device__ __forceinline__ void sort64_desc(unsigned long long& kv, int lane) {
    #pragma unroll
    for (int k = 2; k <= 64; k <<= 1) {
        #pragma unroll
        for (int j = k >> 1; j > 0; j >>= 1) {
            unsigned long long o = __shfl_xor(kv, j);
            bool tmax = (((lane & j) == 0) != ((lane & k) != 0));
            kv = tmax ? kmax(kv, o) : kmin(kv, o);
        }
    }
}

// ---- one block (4 waves) per node ----
__global__ __launch_bounds__(NT, 8)
void fused_kernel(const float* __restrict__ x,
                  const uvec4* __restrict__ adj4,
                  const int*   __restrict__ cs,
                  int*         __restrict__ out)
{
    const int i    = blockIdx.x;           // node id
    const int t    = threadIdx.x;
    const int w    = t >> 6;
    const int lane = t & 63;

    __shared__ unsigned mask[NN / 32];                  // 1 KB dedup bitmap
    __shared__ int nbrs[MAXNBR];
    __shared__ int nnbr;
    __shared__ alignas(16) int cand[MAXC];              // unique candidate values
    __shared__ int ncand;
    __shared__ unsigned long long histsurv[NBINS / 2];  // 8 KB: hist (u32x2048) then surv (u64x544)
    __shared__ unsigned sum256[NT];                     // stage-1 partial sums
    __shared__ int nsurv;
    __shared__ int B_sh;
    unsigned* const hist = reinterpret_cast<unsigned*>(histsurv);
    unsigned long long* const surv = histsurv;

    // ---- issue global loads FIRST: row stream + xi4; their latency hides
    //      under the LDS clears below ----
    const uvec4* __restrict__ row4 = adj4 + (size_t)i * (NN / 4);
    uvec4 v[8];
    #pragma unroll
    for (int u = 0; u < 8; ++u) v[u] = __builtin_nontemporal_load(&row4[t + NT * u]);
    const int gl = t & 15;                              // lane in 16-lane group
    const float4 xi4 = reinterpret_cast<const float4*>(x + (size_t)i * DF)[gl];

    // ---- phase A: init (cand zero-filled: safe prefetch addresses past ncv) ----
    if (t < NN / 32) mask[t] = 0u;                      // 256 words
    #pragma unroll
    for (int r = 0; r < 4; ++r) histsurv[t + NT * r] = 0ULL;  // clears 2048 u32 bins
    cand[t] = 0; cand[t + NT] = 0;
    if (t < MAXC - 2 * NT) cand[t + 2 * NT] = 0;
    if (t == 0) { nbrs[0] = i; nnbr = 1; ncand = 0; nsurv = 0; }
    __syncthreads();                                    // barrier 1 (drains row loads)

    // ---- phase B: extract neighbors from the prefetched row ----
    #pragma unroll
    for (int u = 0; u < 8; ++u) {
        if ((v[u].x | v[u].y | v[u].z | v[u].w) != 0u) {    // 1.0f == 0x3F800000
            const int base = 4 * (t + NT * u);
            const unsigned e[4] = {v[u].x, v[u].y, v[u].z, v[u].w};
            #pragma unroll
            for (int c2 = 0; c2 < 4; ++c2) {
                if (e[c2] != 0u) {
                    int s = atomicAdd(&nnbr, 1);
                    if (s < MAXNBR) nbrs[s] = base + c2;
                }
            }
        }
    }
    __syncthreads();                                    // barrier 2

    const int M = min(nnbr, MAXNBR);
    const int total = M * KK;                           // <= 528

    // ---- phase C: gather cs, dedup via bitmap, append uniques (R16 form) ----
    #pragma unroll
    for (int r = 0; r < 2; ++r) {
        int q = t + NT * r;
        if (q < total) {
            int vv = cs[(size_t)nbrs[q >> 4] * KK + (q & 15)];
            unsigned bit = 1u << (vv & 31);
            unsigned old = atomicOr(&mask[vv >> 5], bit);
            if (!(old & bit)) { int s = atomicAdd(&ncand, 1); cand[s] = vv; }
        }
    }
    const int q2 = 2 * NT + (t - 64);                   // 512..527 for t=64..79
    if (t >= 64 && t < 80 && q2 < total) {
        int vv = cs[(size_t)nbrs[q2 >> 4] * KK + (q2 & 15)];
        unsigned bit = 1u << (vv & 31);
        unsigned old = atomicOr(&mask[vv >> 5], bit);
        if (!(old & bit)) { int s = atomicAdd(&ncand, 1); cand[s] = vv; }
    }
    __syncthreads();                                    // barrier 3

    const int ncv = ncand;                              // unique count

    // ---- phase D: sims — 16-lane groups, 4 candidates per int4 LDS read,
    //      DPP row-reduce; keys kept in REGISTERS (no skeys LDS) ----
    const int g  = t >> 4;                              // 16 groups
    unsigned long long rkeys[NR];                       // statically indexed
    #pragma unroll
    for (int r = 0; r < NR; ++r) {
        unsigned long long key = 0ULL;
        const int c0 = 4 * g + 64 * r;
        if (c0 < ncv) {
            const int4 c4 = *reinterpret_cast<const int4*>(&cand[c0]);  // ds_read_b128
            const float4 xv0 = reinterpret_cast<const float4*>(x + (size_t)c4.x * DF)[gl];
            const float4 xv1 = reinterpret_cast<const float4*>(x + (size_t)c4.y * DF)[gl];
            const float4 xv2 = reinterpret_cast<const float4*>(x + (size_t)c4.z * DF)[gl];
            const float4 xv3 = reinterpret_cast<const float4*>(x + (size_t)c4.w * DF)[gl];
            float a0 = 0.f, a1 = 0.f, a2 = 0.f, a3 = 0.f;
            a0 = fmaf(xi4.x, xv0.x, a0); a0 = fmaf(xi4.y, xv0.y, a0);
            a0 = fmaf(xi4.z, xv0.z, a0); a0 = fmaf(xi4.w, xv0.w, a0);
            a1 = fmaf(xi4.x, xv1.x, a1); a1 = fmaf(xi4.y, xv1.y, a1);
            a1 = fmaf(xi4.z, xv1.z, a1); a1 = fmaf(xi4.w, xv1.w, a1);
            a2 = fmaf(xi4.x, xv2.x, a2); a2 = fmaf(xi4.y, xv2.y, a2);
            a2 = fmaf(xi4.z, xv2.z, a2); a2 = fmaf(xi4.w, xv2.w, a2);
            a3 = fmaf(xi4.x, xv3.x, a3); a3 = fmaf(xi4.y, xv3.y, a3);
            a3 = fmaf(xi4.z, xv3.z, a3); a3 = fmaf(xi4.w, xv3.w, a3);
            a0 = row_reduce16(a0);                      // all 16 lanes get the sum
            a1 = row_reduce16(a1);
            a2 = row_reduce16(a2);
            a3 = row_reduce16(a3);
            // lane gl (< 4) owns candidate c0+gl: one key per lane, in registers
            if (gl < 4 && c0 + gl < ncv) {
                float av = (gl == 0) ? a0 : (gl == 1) ? a1 : (gl == 2) ? a2 : a3;
                int  vb = (gl == 0) ? c4.x : (gl == 1) ? c4.y : (gl == 2) ? c4.z : c4.w;
                unsigned fb = __float_as_uint(av);
                fb = (fb & 0x80000000u) ? ~fb : (fb | 0x80000000u);  // order-preserving
                key = ((unsigned long long)fb << 13) |
                      (unsigned long long)(unsigned)(8191 - vb);
                atomicAdd(&hist[HIDX((unsigned)(key >> 34))], 1u);   // 16 lanes, 1 instr
            }
        }
        rkeys[r] = key;                                 // 0 = invalid (unreachable code)
    }
    __syncthreads();                                    // barrier 4

    if (ncv >= KK) {
        // ---- phase F: find bin B containing the 16th-largest key ----
        unsigned s8 = 0;
        #pragma unroll
        for (int j = 0; j < 8; ++j) s8 += hist[(j << 8) | t];   // bins 8t..8t+7
        sum256[t] = s8;
        __syncthreads();                                // barrier 5
        if (w == 0) {
            // stage 2: 64 chunks of 32 bins, scanned from top
            const int c = 63 - lane;
            unsigned c32 = 0;
            #pragma unroll
            for (int j = 0; j < 4; ++j) c32 += sum256[4 * c + j];
            unsigned p = c32;
            #pragma unroll
            for (int off = 1; off < 64; off <<= 1) {
                unsigned o = __shfl_up(p, off);
                if (lane >= off) p += o;
            }
            unsigned long long bal = __ballot(p >= (unsigned)KK);
            int l1 = (int)__ffsll((unsigned long long)bal) - 1;
            unsigned above1 = __shfl(p - c32, l1);
            int C = 63 - l1;
            // stage 3: 32 bins of chunk C, descending
            int b = 32 * C + 31 - lane;
            unsigned hb = (lane < 32) ? hist[HIDX(b)] : 0u;
            unsigned p2 = hb;
            #pragma unroll
            for (int off = 1; off < 64; off <<= 1) {
                unsigned o = __shfl_up(p2, off);
                if (lane >= off) p2 += o;
            }
            unsigned long long bal2 = __ballot(above1 + p2 >= (unsigned)KK);
            int l2 = (int)__ffsll((unsigned long long)bal2) - 1;
            if (lane == 0) B_sh = 32 * C + 31 - l2;
        }
        __syncthreads();                                // barrier 6 (hist now dead)
        const unsigned Bv = (unsigned)B_sh;

        // ---- phase G: append survivors from REGISTERS; surv aliases dead hist ----
        #pragma unroll
        for (int r = 0; r < NR; ++r) {
            unsigned long long k = rkeys[r];
            if (k != 0ULL && (unsigned)(k >> 34) >= Bv) {
                int s = atomicAdd(&nsurv, 1);
                surv[s] = k;
            }
        }
        __syncthreads();                                // barrier 7

        // ---- phase H: wave 0 sorts survivors exactly (u64 keys) ----
        if (w == 0) {
            const int S = nsurv;                        // >= 16 by construction
            unsigned long long kk = (lane < S) ? surv[lane] : 0ULL;
            sort64_desc(kk, lane);
            int processed = 64;
            while (processed < S) {                     // rare fallback: chunked resort
                if (lane >= 16) {
                    int idx = processed + (lane - 16);
                    kk = (idx < S) ? surv[idx] : 0ULL;
                }
                sort64_desc(kk, lane);
                processed += 48;
            }
            if (lane < KK)
                out[(size_t)i * KK + lane] = 8191 - (int)(kk & 0x1FFFULL);
        }
    } else {
        // rare: fewer than K uniques -> sorted uniques + pad with own samples
        if (t == 0) {
            int sorted_u[KK];
            int cnt2 = 0;
            for (int mw = 0; mw < NN / 32 && cnt2 < KK; ++mw) {
                unsigned b = mask[mw];
                while (b && cnt2 < KK) {
                    int bit = __ffs(b) - 1;
                    b &= b - 1;
                    sorted_u[cnt2++] = mw * 32 + bit;
                }
            }
            for (int j = 0; j < KK; ++j) {
                int uu;
                if (j < ncv) {
                    uu = sorted_u[j];
                } else {
                    int idx = j - ncv;
                    if (idx > KK - 1) idx = KK - 1;
                    uu = cs[(size_t)i * KK + idx];
                }
                out[(size_t)i * KK + j] = uu;
            }
        }
    }
}

extern "C" void kernel_launch(void* const* d_in, const int* in_sizes, int n_in,
                              void* d_out, int out_size, void* d_ws, size_t ws_size,
                              hipStream_t stream)
{
    const float* x   = (const float*)d_in[0];
    const float* adj = (const float*)d_in[1];
    const int*   cs  = (const int*)d_in[2];
    int* out = (int*)d_out;

    fused_kernel<<<NN, NT, 0, stream>>>(
        x, reinterpret_cast<const uvec4*>(adj), cs, out);
}